// Round 16
// baseline (112.552 us; speedup 1.0000x reference)
//
#include <hip/hip_runtime.h>
#include <math.h>

// BIMM2D: M=250000 points, P=4 interior phases, K=6 interface pairs, N_MC=64
#define KN 384            // K * N_MC table entries
#define TPB 256
#define PPB 128           // points per block (two entry-halves per point)

// Device-global scratch. g_ctr is module-init 0 and self-restored by the last
// block each launch -> graph-replay safe, independent of d_ws poison.
__device__ float  g_tx[KN], g_ty[KN], g_tz[KN];   // SoA table (read via s_load)
__device__ float  g_hdr[12];                      // folded constants
__device__ double g_part[2048];
__device__ int    g_ctr = 0;

__device__ __forceinline__ float fexp2(float x) {
  return __builtin_amdgcn_exp2f(x);   // native v_exp_f32
}

// ---------------------------------------------------------------------------
// Prep kernel (1 block, 384 threads): exp2-folded table + header in GLOBAL
// memory; main kernel reads it through the scalar pipe.
// g_hdr = { isn*SQH, inv_s2*LOG2E, cq[4], wint[4], -, - }
// g_tx = In/sn*SQH, g_ty = (2G/s2)*log2e, g_tz = wk*exp(-G^2/s2)/G
// ---------------------------------------------------------------------------
__global__ __launch_bounds__(KN) void prep_kernel(
    const float* __restrict__ eps, const float* __restrict__ I,
    const float* __restrict__ W, const float* __restrict__ sb_,
    const float* __restrict__ sn_, const float* __restrict__ d_,
    const float* __restrict__ r_) {
  const int t = threadIdx.x;
  const float sb  = sb_[0];
  const float sn  = sn_[0];
  const float dd  = d_[0];
  const float rho = tanhf(r_[0]);
  const float s2  = sn * sn * (1.f - rho);      // sr^2
  const float sr  = sqrtf(s2);
  const float isn = 1.f / sn;
  const float inv_s2 = 1.f / s2;
  const float LOG2E = 1.4426950408889634f;
  const float SQH   = sqrtf(0.5f * LOG2E);

  float wmax = W[0];
  for (int j = 1; j < 10; ++j) wmax = fmaxf(wmax, W[j]);
  float se = 0.f;
  for (int j = 0; j < 10; ++j) se += expf(W[j] - wmax);
  const float lse = wmax + logf(se);

  const float LOG2PI_ = 1.8378770664093453f;
  const float LOG2_   = 0.6931471805599453f;
  const float LGG32   = -0.12078223763524522f;  // log(gamma(1.5))
  const float LOGPI_  = 1.1447298858494002f;
  const float Cterm = -logf(sn) - 0.5f * LOG2PI_ - logf(sr) - 0.5f * LOGPI_;
  const float Cint0 = LOG2_ - LGG32 - 3.f * logf(sr) - logf(sn) - 0.5f * LOG2PI_;

  if (t < 12) {
    float h = 0.f;
    if      (t == 0) h = isn * SQH;
    else if (t == 1) h = inv_s2 * LOG2E;
    else if (t < 6)  h = I[t - 2] * isn * SQH;          // cq[0..3]
    else if (t < 10) h = expf(W[t - 6] - lse + Cint0);  // wint[0..3]
    g_hdr[t] = h;
  }

  const int IAc[6] = {0, 0, 0, 1, 1, 2};
  const int IBc[6] = {1, 2, 3, 2, 3, 3};
  const int k = t >> 6;
  const float Ia = I[IAc[k]], Ib = I[IBc[k]];
  const float wk = expf(W[4 + k] - lse + Cterm) * (1.0f / 64.0f);
  const float e  = eps[t];
  const float x  = e * 2.f * dd * sb - dd * sb;
  const float y  = x / (1.4142135623730951f * sb);
  const float In = (erff(y) + 1.f) * 0.5f * (Ib - Ia) + Ia;
  const float qq = 2.f * (In - Ia) / (Ib - Ia) - 1.f;
  const float gi = erfinvf(qq);
  const float G  = (Ib - Ia) * 0.3989422804014327f / sb * expf(-gi * gi);
  g_tx[t] = In * isn * SQH;
  g_ty[t] = 2.f * inv_s2 * G * LOG2E;
  g_tz[t] = wk * expf(-G * G * inv_s2) / G;
}

// ---------------------------------------------------------------------------
// Main kernel (R16): R14's exact per-entry body (scalar ENT, s_load table,
// unroll 6) with ONLY the entry-split added - the clean TLP test R12
// confounded with v2f marshalling. 128 points/block, h = tid>>7 selects
// entries [h*192,(h+1)*192): 1954 blocks ~= 7.6 blocks/CU; launch_bounds
// (256,8) -> 64-VGPR cap (live set ~45, no spill) -> up to 8 waves/SIMD
// resident to cover the dependency-chain idle (~40% in all prior variants).
// readfirstlane(h) keeps the table base provably wave-uniform (s_load).
// h=1 waves own the point prelude and the final log; one barrier combines.
// ---------------------------------------------------------------------------
__global__ __launch_bounds__(TPB, 8) void main_kernel(
    const float* __restrict__ u, const float* __restrict__ v,
    float* __restrict__ out, int M, int nb) {
  __shared__ float  sS[PPB];
  __shared__ double red[TPB];
  __shared__ int    slast;
  const int tid = threadIdx.x;
  const int pi  = tid & (PPB - 1);
  const int hu  = __builtin_amdgcn_readfirstlane(tid >> 7);  // wave-uniform half
  const int i   = blockIdx.x * PPB + pi;
  const bool act = i < M;

  float uu = 0.f, vv = 1.f;
  if (act) { uu = u[i]; vv = v[i]; }

  // header via scalar loads (uniform)
  const float husc = g_hdr[0];   // isn*SQH
  const float hg   = g_hdr[1];   // inv_s2*LOG2E
  const float us   = uu * husc;

  // prelude only on the h=1 waves (they also do the log at the end)
  float c0 = 0.f, c1 = 1.f;
  if (hu == 1 && act) {
    const float gg = fexp2(-vv * vv * hg);
    float aint = 0.f;
#pragma unroll
    for (int p = 0; p < 4; ++p) {
      const float dq = us - g_hdr[2 + p];
      aint = fmaf(g_hdr[6 + p], fexp2(-dq * dq), aint);
    }
    c0 = vv * gg;
    c1 = vv * vv * gg * aint;
  }

  // ---- main loop: this half's 192 entries = 24 groups of 8, unroll 6 ----
  const float* ptx = g_tx + hu * (KN / 2);
  const float* pty = g_ty + hu * (KN / 2);
  const float* ptz = g_tz + hu * (KN / 2);
  float S0 = 0.f, S1 = 0.f, S2 = 0.f, S3 = 0.f;
  float S4 = 0.f, S5 = 0.f, S6 = 0.f, S7 = 0.f;
#define ENT(TX, TY, TZ, S)                         \
  {                                                \
    const float du = us - (TX);                    \
    const float nd = du * -du;                     \
    const float a1 = fmaf(vv, (TY), nd);           \
    const float a2 = fmaf(vv, -(TY), nd);          \
    S = fmaf((TZ), fexp2(a1), S);                  \
    S = fmaf(-(TZ), fexp2(a2), S);                 \
  }
#pragma unroll 6
  for (int g = 0; g < KN / 16; ++g) {   // 24 groups of 8 entries
    const int b = g * 8;
    float X[8], Y[8], Z[8];
#pragma unroll
    for (int j = 0; j < 8; ++j) {       // -> s_load_dwordx8 x3 per group
      X[j] = ptx[b + j];
      Y[j] = pty[b + j];
      Z[j] = ptz[b + j];
    }
    ENT(X[0], Y[0], Z[0], S0) ENT(X[1], Y[1], Z[1], S1)
    ENT(X[2], Y[2], Z[2], S2) ENT(X[3], Y[3], Z[3], S3)
    ENT(X[4], Y[4], Z[4], S4) ENT(X[5], Y[5], Z[5], S5)
    ENT(X[6], Y[6], Z[6], S6) ENT(X[7], Y[7], Z[7], S7)
  }
#undef ENT
  const float Sh = ((S0 + S1) + (S2 + S3)) + ((S4 + S5) + (S6 + S7));

  // ---- combine halves; h=1 produces the per-point log ----
  if (hu == 0) sS[pi] = Sh;
  __syncthreads();
  double mysum = 0.0;
  if (hu == 1) {
    const float S = sS[pi] + Sh;
    mysum = (double)__logf(fmaf(c0, S, c1));   // inactive: log(1) = 0
  }

  // ---- block reduction (deterministic tree) ----
  red[tid] = mysum;
  __syncthreads();
  for (int s = TPB / 2; s > 0; s >>= 1) {
    if (tid < s) red[tid] += red[tid + s];
    __syncthreads();
  }
  if (tid == 0)
    __hip_atomic_store(&g_part[blockIdx.x], red[0], __ATOMIC_RELAXED,
                       __HIP_MEMORY_SCOPE_AGENT);

  // ---- last-block-done final reduction (fixed order -> deterministic) ----
  if (tid == 0) {
    const int c = __hip_atomic_fetch_add(&g_ctr, 1, __ATOMIC_ACQ_REL,
                                         __HIP_MEMORY_SCOPE_AGENT);
    slast = (c == nb - 1) ? 1 : 0;
  }
  __syncthreads();
  if (slast) {
    double s = 0.0;
    for (int j = tid; j < nb; j += TPB)
      s += __hip_atomic_load(&g_part[j], __ATOMIC_RELAXED,
                             __HIP_MEMORY_SCOPE_AGENT);
    red[tid] = s;
    __syncthreads();
    for (int k2 = TPB / 2; k2 > 0; k2 >>= 1) {
      if (tid < k2) red[tid] += red[tid + k2];
      __syncthreads();
    }
    if (tid == 0) {
      out[0] = (float)(-red[0] / (double)M);
      __hip_atomic_store(&g_ctr, 0, __ATOMIC_RELAXED,
                         __HIP_MEMORY_SCOPE_AGENT);  // restore for next replay
    }
  }
}

extern "C" void kernel_launch(void* const* d_in, const int* in_sizes, int n_in,
                              void* d_out, int out_size, void* d_ws, size_t ws_size,
                              hipStream_t stream) {
  const float* u   = (const float*)d_in[0];
  const float* v   = (const float*)d_in[1];
  const float* eps = (const float*)d_in[2];
  const float* I   = (const float*)d_in[3];
  const float* W   = (const float*)d_in[4];
  const float* sb  = (const float*)d_in[5];
  const float* sn  = (const float*)d_in[6];
  const float* dd  = (const float*)d_in[7];
  const float* r   = (const float*)d_in[8];
  const int M  = in_sizes[0];
  const int nb = (M + PPB - 1) / PPB;   // 1954 for M=250000 (g_part holds 2048)

  hipLaunchKernelGGL(prep_kernel, dim3(1), dim3(KN), 0, stream,
                     eps, I, W, sb, sn, dd, r);
  hipLaunchKernelGGL(main_kernel, dim3(nb), dim3(TPB), 0, stream,
                     u, v, (float*)d_out, M, nb);
}